// Round 9
// baseline (334.572 us; speedup 1.0000x reference)
//
#include <hip/hip_runtime.h>
#include <hip/hip_bf16.h>

#define B_SZ 4096
#define N_SZ 200

// workspace offsets (4-byte units)
#define OFF_BFRAG 0        // 12288 u32: W-fragments, 3 layers x 2kt x 4ct x 2(hi/lo) x 64 lanes x 4 u32
#define OFF_AW1BT 12288    // 4096 f32: aw1bT[d][k] = att_w1[k][64+d]  (for qc prep)
#define OFF_ERC   16384    // 384  f32: erc[r][k]
#define OFF_QC    16768    // B*64 f32: qc[b][k]

typedef __attribute__((ext_vector_type(8))) __bf16 bf16x8;
typedef __attribute__((ext_vector_type(4))) float f32x4;
typedef __attribute__((ext_vector_type(4))) unsigned u32x4;

__device__ __forceinline__ void split2(float x, unsigned &hi, unsigned &lo) {
    unsigned u = __float_as_uint(x);
    hi = (u + 0x7FFFu + ((u >> 16) & 1u)) >> 16;
    float r = x - __uint_as_float(hi << 16);
    unsigned ul = __float_as_uint(r);
    lo = (ul + 0x7FFFu + ((ul >> 16) & 1u)) >> 16;
}

__device__ __forceinline__ unsigned packbf(float e0, float e1) {
    __bf16 h0 = (__bf16)e0, h1 = (__bf16)e1;
    return ((unsigned)__builtin_bit_cast(unsigned short, h1) << 16) |
           (unsigned)__builtin_bit_cast(unsigned short, h0);
}

// ---------- prep (unchanged) ----------
__global__ void prep1(const float* __restrict__ gu_w1, const float* __restrict__ gu_b1,
                      const float* __restrict__ gu_w2, const float* __restrict__ att_w1,
                      const float* __restrict__ rate_emb, float* __restrict__ ws) {
    int t = threadIdx.x;  // 1 block x 256
    unsigned* wsu = (unsigned*)ws;
    for (int i = t; i < 12288; i += 256) {
        int frag = i >> 8, within = i & 255, lane = within >> 2, r = within & 3;
        int hl = frag & 1, ct = (frag >> 1) & 3, kt = (frag >> 3) & 1, layer = frag >> 4;
        int col = ct * 16 + (lane & 15);
        int d0 = kt * 32 + 8 * (lane >> 4) + 2 * r;
        float w0, w1v;
        if (layer == 0)      { w0 = gu_w1[col * 128 + d0];  w1v = gu_w1[col * 128 + d0 + 1]; }
        else if (layer == 1) { w0 = gu_w2[col * 64 + d0];   w1v = gu_w2[col * 64 + d0 + 1]; }
        else                 { w0 = att_w1[col * 128 + d0]; w1v = att_w1[col * 128 + d0 + 1]; }
        unsigned h0, l0, h1, l1;
        split2(w0, h0, l0); split2(w1v, h1, l1);
        unsigned lo16 = hl ? l0 : h0;
        unsigned hi16 = hl ? l1 : h1;
        wsu[OFF_BFRAG + i] = lo16 | (hi16 << 16);
    }
    for (int i = t; i < 4096; i += 256) {
        int d = i >> 6, k = i & 63;
        ws[OFF_AW1BT + i] = att_w1[k * 128 + 64 + d];
    }
    for (int i = t; i < 384; i += 256) {
        int rr = i >> 6, k = i & 63;
        float a = gu_b1[k];
        for (int d = 0; d < 64; ++d)
            a += gu_w1[k * 128 + 64 + d] * rate_emb[rr * 64 + d];
        ws[OFF_ERC + i] = a;
    }
}

__global__ void prep2_qc(const int* __restrict__ iids, const float* __restrict__ item_emb,
                         const float* __restrict__ ws, float* __restrict__ qc) {
    int b = blockIdx.x, k = threadIdx.x;
    int iid = iids[b];
    const float* awbT = ws + OFF_AW1BT;
    const float* irow = item_emb + (size_t)iid * 64;
    float acc = 0.f;
    for (int d = 0; d < 64; ++d)
        acc = fmaf(awbT[d * 64 + k], irow[d], acc);
    qc[b * 64 + k] = acc;
}

// ---------- fused main: transposed dataflow, register-resident layer chain ----------
// h^T = W1 . X^T : A-operand = W (existing frag table IS the A-frag), B-operand = X
// (A-frag(X) == B-frag(X^T) identity). C output: col = n = lane&15, row = k_out.
// Inter-layer C->B relayout via 16 shfl + 8 selects per plane (register-only).
__global__ __launch_bounds__(256, 2) void fused_main(
    const int* __restrict__ pad, const float* __restrict__ user_emb,
    const float* __restrict__ gu_b2, const float* __restrict__ att_b1,
    const float* __restrict__ att_w2, const float* __restrict__ att_b2,
    const float* __restrict__ agg_w, const float* __restrict__ agg_b,
    const float* __restrict__ ws, float* __restrict__ out) {

    __shared__ __align__(16) unsigned wsW[12288];  // 48 KB: all 3 layers' W frags
    __shared__ float erc_s[6 * 65];
    __shared__ float b2_s[64], aw2_s[64];
    __shared__ float2 aq_s[64];                     // (ab1[k], qc[b][k])
    __shared__ float aggp[4][64];
    __shared__ float agg_s[64];
    __shared__ float red_s[4];

    const int b = blockIdx.x;
    const int tid = threadIdx.x;
    const int w = tid >> 6;
    const int lane = tid & 63;
    const int n = lane & 15;        // column (row-id of the problem) this lane owns
    const int lgrp = lane >> 4;     // quarter-wave group
    const float ab2 = att_b2[0];

    // ---- one-time cooperative staging + single barrier ----
    {
        const u32x4* src = (const u32x4*)((const unsigned*)ws + OFF_BFRAG);
        u32x4* dst = (u32x4*)wsW;
#pragma unroll
        for (int i = 0; i < 12; ++i) dst[tid + 256 * i] = src[tid + 256 * i];
        for (int i = tid; i < 384; i += 256)
            erc_s[(i >> 6) * 65 + (i & 63)] = ws[OFF_ERC + i];
        if (tid < 64) {
            b2_s[tid]  = gu_b2[tid];
            aw2_s[tid] = att_w2[tid];
            aq_s[tid]  = make_float2(att_b1[tid], ws[OFF_QC + b * 64 + tid]);
        }
    }
    __syncthreads();

#define LOAD_W(LAYER)                                                            \
    u32x4 bh[4][2], bl[4][2];                                                    \
    _Pragma("unroll")                                                            \
    for (int ct = 0; ct < 4; ++ct)                                               \
        _Pragma("unroll")                                                        \
        for (int kt = 0; kt < 2; ++kt) {                                         \
            int fb = (((LAYER) * 2 + kt) * 4 + ct) * 2;                          \
            bh[ct][kt] = *(const u32x4*)&wsW[(fb + 0) * 256 + lane * 4];         \
            bl[ct][kt] = *(const u32x4*)&wsW[(fb + 1) * 256 + lane * 4];         \
        }

#define MFMA3_T(ACC, XH_, XL_)                                                   \
    _Pragma("unroll")                                                            \
    for (int ct = 0; ct < 4; ++ct)                                               \
        _Pragma("unroll")                                                        \
        for (int kt = 0; kt < 2; ++kt) {                                         \
            bf16x8 WH = __builtin_bit_cast(bf16x8, bh[ct][kt]);                  \
            bf16x8 WL = __builtin_bit_cast(bf16x8, bl[ct][kt]);                  \
            ACC[ct] = __builtin_amdgcn_mfma_f32_16x16x32_bf16(WL, XH_[kt], ACC[ct], 0, 0, 0); \
            ACC[ct] = __builtin_amdgcn_mfma_f32_16x16x32_bf16(WH, XL_[kt], ACC[ct], 0, 0, 0); \
            ACC[ct] = __builtin_amdgcn_mfma_f32_16x16x32_bf16(WH, XH_[kt], ACC[ct], 0, 0, 0); \
        }

#define MFMA2_T(ACC, XH_)                                                        \
    _Pragma("unroll")                                                            \
    for (int ct = 0; ct < 4; ++ct)                                               \
        _Pragma("unroll")                                                        \
        for (int kt = 0; kt < 2; ++kt) {                                         \
            bf16x8 WH = __builtin_bit_cast(bf16x8, bh[ct][kt]);                  \
            bf16x8 WL = __builtin_bit_cast(bf16x8, bl[ct][kt]);                  \
            ACC[ct] = __builtin_amdgcn_mfma_f32_16x16x32_bf16(WL, XH_[kt], ACC[ct], 0, 0, 0); \
            ACC[ct] = __builtin_amdgcn_mfma_f32_16x16x32_bf16(WH, XH_[kt], ACC[ct], 0, 0, 0); \
        }

    // C->B redistribution: target B[kt] u32 j holds d-pair (32kt+8lgrp+2j, +1).
    // src_ct = 2kt + (lgrp>>1); src_lgrp = (2lgrp + (j>>1))&3; pair = j&1.
    // Receiver-side select between p[2kt] / p[2kt+1] resolves src_ct.
    const int slA = ((((lgrp * 2)     ) & 3) << 4) | n;   // j = 0,1
    const int slB = ((((lgrp * 2) + 1 ) & 3) << 4) | n;   // j = 2,3
    const bool hiSel = (lgrp >= 2);
    auto redis = [&](const unsigned p[4][2], bf16x8 outF[2]) {
#pragma unroll
        for (int kt = 0; kt < 2; ++kt) {
            unsigned qa0 = (unsigned)__shfl((int)p[2 * kt + 0][0], slA);
            unsigned qb0 = (unsigned)__shfl((int)p[2 * kt + 1][0], slA);
            unsigned qa1 = (unsigned)__shfl((int)p[2 * kt + 0][1], slA);
            unsigned qb1 = (unsigned)__shfl((int)p[2 * kt + 1][1], slA);
            unsigned qa2 = (unsigned)__shfl((int)p[2 * kt + 0][0], slB);
            unsigned qb2 = (unsigned)__shfl((int)p[2 * kt + 1][0], slB);
            unsigned qa3 = (unsigned)__shfl((int)p[2 * kt + 0][1], slB);
            unsigned qb3 = (unsigned)__shfl((int)p[2 * kt + 1][1], slB);
            u32x4 q = { hiSel ? qb0 : qa0, hiSel ? qb1 : qa1,
                        hiSel ? qb2 : qa2, hiSel ? qb3 : qa3 };
            outF[kt] = __builtin_bit_cast(bf16x8, q);
        }
    };

    float aggr[4][4];
#pragma unroll
    for (int ct = 0; ct < 4; ++ct)
#pragma unroll
        for (int r = 0; r < 4; ++r) aggr[ct][r] = 0.f;
    float swave = 0.f;

    for (int t = w; t < 13; t += 4) {
        const int ng = t * 16 + n;
        const bool valid = (ng < N_SZ);
        int uid = 0, rid = 0;
        if (valid) {
            int2 pr = ((const int2*)pad)[b * N_SZ + ng];
            uid = pr.x; rid = pr.y;
        }
        const float maskn = (valid && uid > 0) ? 1.f : 0.f;

        // ---- stage this lane's X B-frags straight from global ----
        bf16x8 XH[2], XL[2];
#pragma unroll
        for (int kt = 0; kt < 2; ++kt) {
            float4 a = make_float4(0.f, 0.f, 0.f, 0.f), c = a;
            if (valid) {
                const float* rp = user_emb + (size_t)uid * 64 + kt * 32 + lgrp * 8;
                a = *(const float4*)rp;
                c = *(const float4*)(rp + 4);
            }
            float v0 = a.x, v1 = a.y, v2 = a.z, v3 = a.w;
            float v4 = c.x, v5 = c.y, v6 = c.z, v7 = c.w;
            __bf16 t0 = (__bf16)v0, t1 = (__bf16)v1, t2 = (__bf16)v2, t3 = (__bf16)v3;
            __bf16 t4 = (__bf16)v4, t5 = (__bf16)v5, t6 = (__bf16)v6, t7 = (__bf16)v7;
            u32x4 hq = { packbf(v0, v1), packbf(v2, v3), packbf(v4, v5), packbf(v6, v7) };
            u32x4 lq = { packbf(v0 - (float)t0, v1 - (float)t1),
                         packbf(v2 - (float)t2, v3 - (float)t3),
                         packbf(v4 - (float)t4, v5 - (float)t5),
                         packbf(v6 - (float)t6, v7 - (float)t7) };
            XH[kt] = __builtin_bit_cast(bf16x8, hq);
            XL[kt] = __builtin_bit_cast(bf16x8, lq);
        }

        // ---- layer 1: h^T = relu(W1 . X^T + erc[rid[n]]) ----
        f32x4 acc1[4];
#pragma unroll
        for (int ct = 0; ct < 4; ++ct)
#pragma unroll
            for (int r = 0; r < 4; ++r)
                acc1[ct][r] = erc_s[rid * 65 + ct * 16 + lgrp * 4 + r];
        {
            LOAD_W(0)
            MFMA3_T(acc1, XH, XL)
        }
        unsigned pH[4][2], pL[4][2];
#pragma unroll
        for (int ct = 0; ct < 4; ++ct) {
            float h0 = fmaxf(acc1[ct][0], 0.f), h1 = fmaxf(acc1[ct][1], 0.f);
            float h2 = fmaxf(acc1[ct][2], 0.f), h3 = fmaxf(acc1[ct][3], 0.f);
            __bf16 u0 = (__bf16)h0, u1 = (__bf16)h1, u2 = (__bf16)h2, u3 = (__bf16)h3;
            pH[ct][0] = packbf(h0, h1);
            pH[ct][1] = packbf(h2, h3);
            pL[ct][0] = packbf(h0 - (float)u0, h1 - (float)u1);
            pL[ct][1] = packbf(h2 - (float)u2, h3 - (float)u3);
        }
        bf16x8 HH[2], HL[2];
        redis(pH, HH);
        redis(pL, HL);

        // ---- layer 2: f^T = W2 . h^T + b2 (kept exact in regs for agg) ----
        f32x4 facc[4];
#pragma unroll
        for (int ct = 0; ct < 4; ++ct) {
#pragma unroll
            for (int r = 0; r < 4; ++r)
                facc[ct][r] = b2_s[ct * 16 + lgrp * 4 + r];
        }
        {
            LOAD_W(1)
            MFMA3_T(facc, HH, HL)
        }
        unsigned pF[4][2];
#pragma unroll
        for (int ct = 0; ct < 4; ++ct) {
            pF[ct][0] = packbf(facc[ct][0], facc[ct][1]);
            pF[ct][1] = packbf(facc[ct][2], facc[ct][3]);
        }
        bf16x8 FH[2];
        redis(pF, FH);

        // ---- layer 3: ah^T = relu(W3 . f^T + ab1 + mask*qc); miu; agg ----
        f32x4 acc3[4];
#pragma unroll
        for (int ct = 0; ct < 4; ++ct) {
#pragma unroll
            for (int r = 0; r < 4; ++r) {
                float2 aq = aq_s[ct * 16 + lgrp * 4 + r];
                acc3[ct][r] = fmaf(maskn, aq.y, aq.x);
            }
        }
        {
            LOAD_W(2)
            MFMA2_T(acc3, FH)
        }
        float pm = 0.f;
#pragma unroll
        for (int ct = 0; ct < 4; ++ct) {
#pragma unroll
            for (int r = 0; r < 4; ++r)
                pm = fmaf(fmaxf(acc3[ct][r], 0.f), aw2_s[ct * 16 + lgrp * 4 + r], pm);
        }
        pm += __shfl_xor(pm, 16);
        pm += __shfl_xor(pm, 32);          // full k-sum, uniform across lgrp lanes
        float miur = __expf(pm + ab2) * maskn;
        swave += (lgrp == 0) ? miur : 0.f; // count each n once
#pragma unroll
        for (int ct = 0; ct < 4; ++ct)
#pragma unroll
            for (int r = 0; r < 4; ++r)
                aggr[ct][r] = fmaf(miur, facc[ct][r], aggr[ct][r]);
    }

    // ---- reductions: over n (xor 1,2,4,8), then cross-wave via LDS ----
#pragma unroll
    for (int ct = 0; ct < 4; ++ct) {
#pragma unroll
        for (int r = 0; r < 4; ++r) {
            float v = aggr[ct][r];
            v += __shfl_xor(v, 1);
            v += __shfl_xor(v, 2);
            v += __shfl_xor(v, 4);
            v += __shfl_xor(v, 8);
            aggr[ct][r] = v;
        }
    }
    float sv = swave;
    sv += __shfl_xor(sv, 1);
    sv += __shfl_xor(sv, 2);
    sv += __shfl_xor(sv, 4);
    sv += __shfl_xor(sv, 8);
    sv += __shfl_xor(sv, 16);
    sv += __shfl_xor(sv, 32);
    if (lane == 0) red_s[w] = sv;
    if (n == 0) {
#pragma unroll
        for (int ct = 0; ct < 4; ++ct)
#pragma unroll
            for (int r = 0; r < 4; ++r)
                aggp[w][ct * 16 + lgrp * 4 + r] = aggr[ct][r];
    }
    __syncthreads();

    const float inv = 1.f / (red_s[0] + red_s[1] + red_s[2] + red_s[3] + 1e-10f);
    if (tid < 64)
        agg_s[tid] = (aggp[0][tid] + aggp[1][tid] + aggp[2][tid] + aggp[3][tid]) * inv;
    __syncthreads();

    // ---- z = relu(agg @ agg_w^T + agg_b) ----
    if (tid < 64) {
        const int k = tid;
        float z = agg_b[k];
        const float4* wr = (const float4*)(agg_w + k * 64);
#pragma unroll
        for (int i = 0; i < 16; ++i) {
            float4 wv = wr[i];
            z = fmaf(wv.x, agg_s[4 * i + 0], z);
            z = fmaf(wv.y, agg_s[4 * i + 1], z);
            z = fmaf(wv.z, agg_s[4 * i + 2], z);
            z = fmaf(wv.w, agg_s[4 * i + 3], z);
        }
        out[b * 64 + k] = fmaxf(z, 0.f);
    }
}

extern "C" void kernel_launch(void* const* d_in, const int* in_sizes, int n_in,
                              void* d_out, int out_size, void* d_ws, size_t ws_size,
                              hipStream_t stream) {
    const int*   iids     = (const int*)d_in[0];
    const int*   pad      = (const int*)d_in[1];
    const float* user_emb = (const float*)d_in[2];
    const float* item_emb = (const float*)d_in[3];
    const float* rate_emb = (const float*)d_in[4];
    const float* gu_w1    = (const float*)d_in[5];
    const float* gu_b1    = (const float*)d_in[6];
    const float* gu_w2    = (const float*)d_in[7];
    const float* gu_b2    = (const float*)d_in[8];
    const float* att_w1   = (const float*)d_in[9];
    const float* att_b1   = (const float*)d_in[10];
    const float* att_w2   = (const float*)d_in[11];
    const float* att_b2   = (const float*)d_in[12];
    const float* agg_w    = (const float*)d_in[13];
    const float* agg_b    = (const float*)d_in[14];
    float* ws  = (float*)d_ws;
    float* out = (float*)d_out;

    hipLaunchKernelGGL(prep1, dim3(1), dim3(256), 0, stream,
                       gu_w1, gu_b1, gu_w2, att_w1, rate_emb, ws);
    hipLaunchKernelGGL(prep2_qc, dim3(B_SZ), dim3(64), 0, stream,
                       iids, item_emb, ws, ws + OFF_QC);
    hipLaunchKernelGGL(fused_main, dim3(B_SZ), dim3(256), 0, stream,
                       pad, user_emb, gu_b2, att_b1, att_w2, att_b2, agg_w, agg_b, ws, out);
}

// Round 10
// 165.100 us; speedup vs baseline: 2.0265x; 2.0265x over previous
//
#include <hip/hip_runtime.h>
#include <hip/hip_bf16.h>

#define B_SZ 4096
#define N_SZ 200

// workspace offsets (4-byte units)
#define OFF_BFRAG 0        // 12288 u32: W-fragments, 3 layers x 2kt x 4ct x 2(hi/lo) x 64 lanes x 4 u32
#define OFF_AW1BT 12288    // 4096 f32: aw1bT[d][k] = att_w1[k][64+d]  (for qc prep)
#define OFF_ERC   16384    // 384  f32: erc[r][k]
#define OFF_QC    16768    // B*64 f32: qc[b][k]
#define OFF_AGG   278912   // B*64 f32: unnormalized sum miu*f (atomic)
#define OFF_SC    541056   // B    f32: sum miu (atomic)
// total 545152 floats = 2.18 MB

typedef __attribute__((ext_vector_type(8))) __bf16 bf16x8;
typedef __attribute__((ext_vector_type(4))) __bf16 bf16x4;
typedef __attribute__((ext_vector_type(4))) float f32x4;
typedef __attribute__((ext_vector_type(4))) unsigned u32x4;

__device__ __forceinline__ void split2(float x, unsigned &hi, unsigned &lo) {
    unsigned u = __float_as_uint(x);
    hi = (u + 0x7FFFu + ((u >> 16) & 1u)) >> 16;
    float r = x - __uint_as_float(hi << 16);
    unsigned ul = __float_as_uint(r);
    lo = (ul + 0x7FFFu + ((ul >> 16) & 1u)) >> 16;
}

// ---------- prep (unchanged, proven) ----------
__global__ void prep1(const float* __restrict__ gu_w1, const float* __restrict__ gu_b1,
                      const float* __restrict__ gu_w2, const float* __restrict__ att_w1,
                      const float* __restrict__ rate_emb, float* __restrict__ ws) {
    int t = threadIdx.x;  // 1 block x 256
    unsigned* wsu = (unsigned*)ws;
    for (int i = t; i < 12288; i += 256) {
        int frag = i >> 8, within = i & 255, lane = within >> 2, r = within & 3;
        int hl = frag & 1, ct = (frag >> 1) & 3, kt = (frag >> 3) & 1, layer = frag >> 4;
        int col = ct * 16 + (lane & 15);
        int d0 = kt * 32 + 8 * (lane >> 4) + 2 * r;
        float w0, w1v;
        if (layer == 0)      { w0 = gu_w1[col * 128 + d0];  w1v = gu_w1[col * 128 + d0 + 1]; }
        else if (layer == 1) { w0 = gu_w2[col * 64 + d0];   w1v = gu_w2[col * 64 + d0 + 1]; }
        else                 { w0 = att_w1[col * 128 + d0]; w1v = att_w1[col * 128 + d0 + 1]; }
        unsigned h0, l0, h1, l1;
        split2(w0, h0, l0); split2(w1v, h1, l1);
        unsigned lo16 = hl ? l0 : h0;
        unsigned hi16 = hl ? l1 : h1;
        wsu[OFF_BFRAG + i] = lo16 | (hi16 << 16);
    }
    for (int i = t; i < 4096; i += 256) {
        int d = i >> 6, k = i & 63;
        ws[OFF_AW1BT + i] = att_w1[k * 128 + 64 + d];
    }
    for (int i = t; i < 384; i += 256) {
        int rr = i >> 6, k = i & 63;
        float a = gu_b1[k];
        for (int d = 0; d < 64; ++d)
            a += gu_w1[k * 128 + 64 + d] * rate_emb[rr * 64 + d];
        ws[OFF_ERC + i] = a;
    }
}

__global__ void prep2_qc(const int* __restrict__ iids, const float* __restrict__ item_emb,
                         const float* __restrict__ ws, float* __restrict__ qc) {
    int b = blockIdx.x, k = threadIdx.x;
    int iid = iids[b];
    const float* awbT = ws + OFF_AW1BT;
    const float* irow = item_emb + (size_t)iid * 64;
    float acc = 0.f;
    for (int d = 0; d < 64; ++d)
        acc = fmaf(awbT[d * 64 + k], irow[d], acc);
    qc[b * 64 + k] = acc;
}

// ---------- main: 1 wave per block, 2 tiles per wave, ~11 KB LDS ----------
// Round-4 body verbatim per tile (only stable register allocation found:
// every loop-wrapped / capped / shuffled variant spilled 300-1000 MB).
// Softmax coupling via f32 atomics into ws (memset-zeroed per launch).
__global__ void fused_main(
    const int* __restrict__ pad, const float* __restrict__ user_emb,
    const float* __restrict__ gu_b2, const float* __restrict__ att_b1,
    const float* __restrict__ att_w2, const float* __restrict__ att_b2,
    const float* __restrict__ ws, float* __restrict__ aggbuf, float* __restrict__ scbuf) {

    __shared__ __align__(16) __bf16 XH[32 * 64];   // 2 tiles x 16 rows
    __shared__ __align__(16) __bf16 XL[32 * 64];
    __shared__ float erc_s[6 * 65];
    __shared__ int   rid_s[32];
    __shared__ float mask_s[32];
    __shared__ float b2_s[64], aw2_s[64], ab1_s[64], qc_s[64];

    const unsigned bx = blockIdx.x;
    const int b = bx / 7;
    const int c = bx - b * 7;          // chunk 0..6
    const bool has2 = (c < 6);         // chunk 6 holds only tile 12
    const int tid = threadIdx.x;       // 0..63 (one wave)
    const int lane = tid;
    const int lrow = lane & 15;
    const int lgrp = lane >> 4;
    const int lcol = lane & 15;
    const unsigned* __restrict__ bfrag = (const unsigned*)ws + OFF_BFRAG;
    const float ab2 = att_b2[0];

    // ---- per-block tiny staging (single wave; LDS deps compiler-ordered) ----
    b2_s[lane]  = gu_b2[lane];
    aw2_s[lane] = att_w2[lane];
    ab1_s[lane] = att_b1[lane];
    qc_s[lane]  = ws[OFF_QC + b * 64 + lane];
#pragma unroll
    for (int i = 0; i < 6; ++i) {
        int j = i * 64 + lane;
        erc_s[(j >> 6) * 65 + (j & 63)] = ws[OFF_ERC + j];
    }

    // ---- stage owned tiles: gather user_emb, hw-cvt split, swizzled LDS ----
    {
        const int dq = lane & 15;      // 4-col group
        const int rowt = lane >> 4;    // 0..3
#pragma unroll
        for (int lt = 0; lt < 2; ++lt) {
            if (lt == 0 || has2) {
                const int gt = 2 * c + lt;
#pragma unroll
                for (int p = 0; p < 4; ++p) {
                    int rr = p * 4 + rowt;         // row in tile
                    int lr = lt * 16 + rr;         // local row 0..31
                    int n  = gt * 16 + rr;         // global row
                    int uid = 0, rid = 0;
                    float4 v = make_float4(0.f, 0.f, 0.f, 0.f);
                    if (n < N_SZ) {
                        int2 pr = ((const int2*)pad)[b * N_SZ + n];
                        uid = pr.x; rid = pr.y;
                        v = *(const float4*)(user_emb + (size_t)uid * 64 + dq * 4);
                    }
                    __bf16 h0 = (__bf16)v.x, h1 = (__bf16)v.y, h2 = (__bf16)v.z, h3 = (__bf16)v.w;
                    bf16x4 hv = { h0, h1, h2, h3 };
                    bf16x4 lv = { (__bf16)(v.x - (float)h0), (__bf16)(v.y - (float)h1),
                                  (__bf16)(v.z - (float)h2), (__bf16)(v.w - (float)h3) };
                    int g = dq >> 1;
                    int idx = lr * 64 + ((g ^ (lr & 7)) << 3) + (dq & 1) * 4;
                    *(bf16x4*)&XH[idx] = hv;
                    *(bf16x4*)&XL[idx] = lv;
                    if (dq == 0) {
                        rid_s[lr]  = (n < N_SZ) ? rid : 0;
                        mask_s[lr] = (n < N_SZ && uid > 0) ? 1.f : 0.f;
                    }
                }
            }
        }
    }
    // no barrier: single wave; compiler inserts lgkmcnt waits for LDS reads.

    auto loadA = [&](const __bf16* P, int lt, bf16x8 A[2]) {
        int ln = lt * 16 + lrow;
        int s = ln & 7;
#pragma unroll
        for (int kt = 0; kt < 2; ++kt)
            A[kt] = *(const bf16x8*)&P[ln * 64 + (((kt * 4 + lgrp) ^ s) << 3)];
    };

#define LOAD_B(LAYER)                                                            \
    u32x4 bh[4][2], bl[4][2];                                                    \
    _Pragma("unroll")                                                            \
    for (int ct = 0; ct < 4; ++ct)                                               \
        _Pragma("unroll")                                                        \
        for (int kt = 0; kt < 2; ++kt) {                                         \
            int fb = (((LAYER) * 2 + kt) * 4 + ct) * 2;                          \
            bh[ct][kt] = *(const u32x4*)&bfrag[(fb + 0) * 256 + lane * 4];       \
            bl[ct][kt] = *(const u32x4*)&bfrag[(fb + 1) * 256 + lane * 4];       \
        }

#define MFMA3(ACC)                                                               \
    _Pragma("unroll")                                                            \
    for (int ct = 0; ct < 4; ++ct)                                               \
        _Pragma("unroll")                                                        \
        for (int kt = 0; kt < 2; ++kt) {                                         \
            bf16x8 BH = __builtin_bit_cast(bf16x8, bh[ct][kt]);                  \
            bf16x8 BL = __builtin_bit_cast(bf16x8, bl[ct][kt]);                  \
            ACC[ct] = __builtin_amdgcn_mfma_f32_16x16x32_bf16(AL[kt], BH, ACC[ct], 0, 0, 0); \
            ACC[ct] = __builtin_amdgcn_mfma_f32_16x16x32_bf16(AH[kt], BL, ACC[ct], 0, 0, 0); \
            ACC[ct] = __builtin_amdgcn_mfma_f32_16x16x32_bf16(AH[kt], BH, ACC[ct], 0, 0, 0); \
        }

#define MFMA2(ACC)                                                               \
    _Pragma("unroll")                                                            \
    for (int ct = 0; ct < 4; ++ct)                                               \
        _Pragma("unroll")                                                        \
        for (int kt = 0; kt < 2; ++kt) {                                         \
            bf16x8 BH = __builtin_bit_cast(bf16x8, bh[ct][kt]);                  \
            bf16x8 BL = __builtin_bit_cast(bf16x8, bl[ct][kt]);                  \
            ACC[ct] = __builtin_amdgcn_mfma_f32_16x16x32_bf16(AH[kt], BL, ACC[ct], 0, 0, 0); \
            ACC[ct] = __builtin_amdgcn_mfma_f32_16x16x32_bf16(AH[kt], BH, ACC[ct], 0, 0, 0); \
        }

    f32x4 f_reg[2][4];   // both tiles' layer-2 outputs (exact f32 for agg)

    // ---- layer 1: h = relu(P @ W1a^T + erc[rid]) ----
    {
        LOAD_B(0)
#pragma unroll
        for (int lt = 0; lt < 2; ++lt) {
            if (lt == 0 || has2) {
                bf16x8 AH[2], AL[2];
                loadA(XH, lt, AH);
                loadA(XL, lt, AL);
                int nr[4], ridr[4];
#pragma unroll
                for (int r = 0; r < 4; ++r) { nr[r] = lt * 16 + lgrp * 4 + r; ridr[r] = rid_s[nr[r]]; }
                f32x4 acc[4];
#pragma unroll
                for (int ct = 0; ct < 4; ++ct) {
                    int k = ct * 16 + lcol;
#pragma unroll
                    for (int r = 0; r < 4; ++r) acc[ct][r] = erc_s[ridr[r] * 65 + k];
                }
                MFMA3(acc)
#pragma unroll
                for (int ct = 0; ct < 4; ++ct) {
                    int col = ct * 16 + lcol;
#pragma unroll
                    for (int r = 0; r < 4; ++r) {
                        float hv = fmaxf(acc[ct][r], 0.f);
                        __bf16 hh = (__bf16)hv;
                        __bf16 ll = (__bf16)(hv - (float)hh);
                        int ln = nr[r];
                        int idx = ln * 64 + (((col >> 3) ^ (ln & 7)) << 3) + (col & 7);
                        XH[idx] = hh;
                        XL[idx] = ll;
                    }
                }
            }
        }
    }

    // ---- layer 2: f = h @ W2^T + b2 (regs; hi stored for layer 3) ----
    {
        LOAD_B(1)
#pragma unroll
        for (int lt = 0; lt < 2; ++lt) {
            if (lt == 0 || has2) {
                bf16x8 AH[2], AL[2];
                loadA(XH, lt, AH);
                loadA(XL, lt, AL);
                f32x4 (&acc)[4] = f_reg[lt];
#pragma unroll
                for (int ct = 0; ct < 4; ++ct) {
                    float bb = b2_s[ct * 16 + lcol];
#pragma unroll
                    for (int r = 0; r < 4; ++r) acc[ct][r] = bb;
                }
                MFMA3(acc)
#pragma unroll
                for (int ct = 0; ct < 4; ++ct) {
                    int col = ct * 16 + lcol;
#pragma unroll
                    for (int r = 0; r < 4; ++r) {
                        int ln = lt * 16 + lgrp * 4 + r;
                        int idx = ln * 64 + (((col >> 3) ^ (ln & 7)) << 3) + (col & 7);
                        XH[idx] = (__bf16)acc[ct][r];   // hi only — layer-3 A operand
                    }
                }
            }
        }
    }

    // ---- layer 3 + miu + in-register agg ----
    float aggr[4] = { 0.f, 0.f, 0.f, 0.f };
    float swave = 0.f;
    {
        LOAD_B(2)
#pragma unroll
        for (int lt = 0; lt < 2; ++lt) {
            if (lt == 0 || has2) {
                bf16x8 AH[2];
                loadA(XH, lt, AH);
                float maskr[4];
#pragma unroll
                for (int r = 0; r < 4; ++r) maskr[r] = mask_s[lt * 16 + lgrp * 4 + r];
                f32x4 acc[4];
#pragma unroll
                for (int ct = 0; ct < 4; ++ct) {
                    int k = ct * 16 + lcol;
                    float bb = ab1_s[k], qq = qc_s[k];
#pragma unroll
                    for (int r = 0; r < 4; ++r) acc[ct][r] = fmaf(maskr[r], qq, bb);
                }
                MFMA2(acc)
                float pm[4] = { 0.f, 0.f, 0.f, 0.f };
#pragma unroll
                for (int ct = 0; ct < 4; ++ct) {
                    float w2v = aw2_s[ct * 16 + lcol];
#pragma unroll
                    for (int r = 0; r < 4; ++r)
                        pm[r] = fmaf(fmaxf(acc[ct][r], 0.f), w2v, pm[r]);
                }
#pragma unroll
                for (int off = 1; off <= 8; off <<= 1) {
#pragma unroll
                    for (int r = 0; r < 4; ++r) pm[r] += __shfl_xor(pm[r], off);
                }
                float miur[4];
#pragma unroll
                for (int r = 0; r < 4; ++r) {
                    miur[r] = __expf(pm[r] + ab2) * maskr[r];
                    swave += miur[r];
                }
#pragma unroll
                for (int ct = 0; ct < 4; ++ct)
#pragma unroll
                    for (int r = 0; r < 4; ++r)
                        aggr[ct] = fmaf(miur[r], f_reg[lt][ct][r], aggr[ct]);
            }
        }
    }

    // ---- reduce over lane groups, then atomic partials into ws ----
#pragma unroll
    for (int ct = 0; ct < 4; ++ct) {
        float v = aggr[ct];
        v += __shfl_xor(v, 16);
        v += __shfl_xor(v, 32);
        aggr[ct] = v;
    }
    swave += __shfl_xor(swave, 16);
    swave += __shfl_xor(swave, 32);
    if (lane < 16) {
#pragma unroll
        for (int ct = 0; ct < 4; ++ct)
            atomicAdd(&aggbuf[b * 64 + ct * 16 + lane], aggr[ct]);
    }
    if (lane == 0)
        atomicAdd(&scbuf[b], swave);
}

// ---- normalize + z = relu(agg @ agg_w^T + agg_b) ----
__global__ __launch_bounds__(256) void final_z(const float* __restrict__ aggbuf,
                                               const float* __restrict__ scbuf,
                                               const float* __restrict__ agg_w,
                                               const float* __restrict__ agg_b,
                                               float* __restrict__ out) {
    __shared__ float aws[64 * 65];
    int t = threadIdx.x;
    for (int idx = t; idx < 4096; idx += 256)
        aws[(idx >> 6) * 65 + (idx & 63)] = agg_w[idx];
    __syncthreads();
    int g = t >> 6, k = t & 63;
    for (int bi = 0; bi < 2; ++bi) {
        int b = blockIdx.x * 8 + g * 2 + bi;
        const float* arow = aggbuf + b * 64;   // wave-uniform -> s_load
        float inv = 1.f / (scbuf[b] + 1e-10f);
        float dot = 0.f;
        for (int d = 0; d < 64; ++d)
            dot = fmaf(aws[k * 65 + d], arow[d], dot);
        out[b * 64 + k] = fmaxf(fmaf(inv, dot, agg_b[k]), 0.f);
    }
}

extern "C" void kernel_launch(void* const* d_in, const int* in_sizes, int n_in,
                              void* d_out, int out_size, void* d_ws, size_t ws_size,
                              hipStream_t stream) {
    const int*   iids     = (const int*)d_in[0];
    const int*   pad      = (const int*)d_in[1];
    const float* user_emb = (const float*)d_in[2];
    const float* item_emb = (const float*)d_in[3];
    const float* rate_emb = (const float*)d_in[4];
    const float* gu_w1    = (const float*)d_in[5];
    const float* gu_b1    = (const float*)d_in[6];
    const float* gu_w2    = (const float*)d_in[7];
    const float* gu_b2    = (const float*)d_in[8];
    const float* att_w1   = (const float*)d_in[9];
    const float* att_b1   = (const float*)d_in[10];
    const float* att_w2   = (const float*)d_in[11];
    const float* att_b2   = (const float*)d_in[12];
    const float* agg_w    = (const float*)d_in[13];
    const float* agg_b    = (const float*)d_in[14];
    float* ws  = (float*)d_ws;
    float* out = (float*)d_out;

    hipLaunchKernelGGL(prep1, dim3(1), dim3(256), 0, stream,
                       gu_w1, gu_b1, gu_w2, att_w1, rate_emb, ws);
    hipLaunchKernelGGL(prep2_qc, dim3(B_SZ), dim3(64), 0, stream,
                       iids, item_emb, ws, ws + OFF_QC);
    hipMemsetAsync(ws + OFF_AGG, 0, (size_t)(B_SZ * 64 + B_SZ) * sizeof(float), stream);
    hipLaunchKernelGGL(fused_main, dim3(B_SZ * 7), dim3(64), 0, stream,
                       pad, user_emb, gu_b2, att_b1, att_w2, att_b2,
                       ws, ws + OFF_AGG, ws + OFF_SC);
    hipLaunchKernelGGL(final_z, dim3(B_SZ / 8), dim3(256), 0, stream,
                       ws + OFF_AGG, ws + OFF_SC, agg_w, agg_b, out);
}

// Round 11
// 156.593 us; speedup vs baseline: 2.1366x; 1.0543x over previous
//
#include <hip/hip_runtime.h>
#include <hip/hip_bf16.h>

#define B_SZ 4096
#define N_SZ 200

// workspace offsets (4-byte units)
#define OFF_BFRAG 0        // 12288 u32: W-fragments, 3 layers x 2kt x 4ct x 2(hi/lo) x 64 lanes x 4 u32
#define OFF_AW1BT 12288    // 4096 f32: aw1bT[d][k] = att_w1[k][64+d]  (for qc prep)
#define OFF_ERC   16384    // 384  f32: erc[r][k]
#define OFF_QC    16768    // B*64 f32: qc[b][k]
#define OFF_AGG   278912   // B*64 f32: unnormalized sum miu*f (atomic)
#define OFF_SC    541056   // B    f32: sum miu (atomic)
// total 545152 floats = 2.18 MB

typedef __attribute__((ext_vector_type(8))) __bf16 bf16x8;
typedef __attribute__((ext_vector_type(4))) __bf16 bf16x4;
typedef __attribute__((ext_vector_type(4))) float f32x4;
typedef __attribute__((ext_vector_type(4))) unsigned u32x4;

__device__ __forceinline__ void split2(float x, unsigned &hi, unsigned &lo) {
    unsigned u = __float_as_uint(x);
    hi = (u + 0x7FFFu + ((u >> 16) & 1u)) >> 16;
    float r = x - __uint_as_float(hi << 16);
    unsigned ul = __float_as_uint(r);
    lo = (ul + 0x7FFFu + ((ul >> 16) & 1u)) >> 16;
}

// ---------- prep (unchanged, proven) ----------
__global__ void prep1(const float* __restrict__ gu_w1, const float* __restrict__ gu_b1,
                      const float* __restrict__ gu_w2, const float* __restrict__ att_w1,
                      const float* __restrict__ rate_emb, float* __restrict__ ws) {
    int t = threadIdx.x;  // 1 block x 256
    unsigned* wsu = (unsigned*)ws;
    for (int i = t; i < 12288; i += 256) {
        int frag = i >> 8, within = i & 255, lane = within >> 2, r = within & 3;
        int hl = frag & 1, ct = (frag >> 1) & 3, kt = (frag >> 3) & 1, layer = frag >> 4;
        int col = ct * 16 + (lane & 15);
        int d0 = kt * 32 + 8 * (lane >> 4) + 2 * r;
        float w0, w1v;
        if (layer == 0)      { w0 = gu_w1[col * 128 + d0];  w1v = gu_w1[col * 128 + d0 + 1]; }
        else if (layer == 1) { w0 = gu_w2[col * 64 + d0];   w1v = gu_w2[col * 64 + d0 + 1]; }
        else                 { w0 = att_w1[col * 128 + d0]; w1v = att_w1[col * 128 + d0 + 1]; }
        unsigned h0, l0, h1, l1;
        split2(w0, h0, l0); split2(w1v, h1, l1);
        unsigned lo16 = hl ? l0 : h0;
        unsigned hi16 = hl ? l1 : h1;
        wsu[OFF_BFRAG + i] = lo16 | (hi16 << 16);
    }
    for (int i = t; i < 4096; i += 256) {
        int d = i >> 6, k = i & 63;
        ws[OFF_AW1BT + i] = att_w1[k * 128 + 64 + d];
    }
    for (int i = t; i < 384; i += 256) {
        int rr = i >> 6, k = i & 63;
        float a = gu_b1[k];
        for (int d = 0; d < 64; ++d)
            a += gu_w1[k * 128 + 64 + d] * rate_emb[rr * 64 + d];
        ws[OFF_ERC + i] = a;
    }
}

__global__ void prep2_qc(const int* __restrict__ iids, const float* __restrict__ item_emb,
                         const float* __restrict__ ws, float* __restrict__ qc) {
    int b = blockIdx.x, k = threadIdx.x;
    int iid = iids[b];
    const float* awbT = ws + OFF_AW1BT;
    const float* irow = item_emb + (size_t)iid * 64;
    float acc = 0.f;
    for (int d = 0; d < 64; ++d)
        acc = fmaf(awbT[d * 64 + k], irow[d], acc);
    qc[b * 64 + k] = acc;
}

// ---------- main: 1 wave per block, 2 tiles per wave, ~11 KB LDS ----------
// Round-10 lesson: WITHOUT __launch_bounds__, hipcc budgets registers for a
// 1024-thread workgroup -> caps at 64 VGPR -> ~490 B/thread scratch spill.
// __launch_bounds__(64) declares the true 1-wave block and unlocks the full
// per-wave register file (round-4 body allocates ~92-130, no spill).
__global__ __launch_bounds__(64) void fused_main(
    const int* __restrict__ pad, const float* __restrict__ user_emb,
    const float* __restrict__ gu_b2, const float* __restrict__ att_b1,
    const float* __restrict__ att_w2, const float* __restrict__ att_b2,
    const float* __restrict__ ws, float* __restrict__ aggbuf, float* __restrict__ scbuf) {

    __shared__ __align__(16) __bf16 XH[32 * 64];   // 2 tiles x 16 rows
    __shared__ __align__(16) __bf16 XL[32 * 64];
    __shared__ float erc_s[6 * 65];
    __shared__ int   rid_s[32];
    __shared__ float mask_s[32];
    __shared__ float b2_s[64], aw2_s[64], ab1_s[64], qc_s[64];

    const unsigned bx = blockIdx.x;
    const int b = bx / 7;
    const int c = bx - b * 7;          // chunk 0..6
    const bool has2 = (c < 6);         // chunk 6 holds only tile 12
    const int tid = threadIdx.x;       // 0..63 (one wave)
    const int lane = tid;
    const int lrow = lane & 15;
    const int lgrp = lane >> 4;
    const int lcol = lane & 15;
    const unsigned* __restrict__ bfrag = (const unsigned*)ws + OFF_BFRAG;
    const float ab2 = att_b2[0];

    // ---- per-block tiny staging (single wave; LDS deps compiler-ordered) ----
    b2_s[lane]  = gu_b2[lane];
    aw2_s[lane] = att_w2[lane];
    ab1_s[lane] = att_b1[lane];
    qc_s[lane]  = ws[OFF_QC + b * 64 + lane];
#pragma unroll
    for (int i = 0; i < 6; ++i) {
        int j = i * 64 + lane;
        erc_s[(j >> 6) * 65 + (j & 63)] = ws[OFF_ERC + j];
    }

    // ---- stage owned tiles: gather user_emb, hw-cvt split, swizzled LDS ----
    {
        const int dq = lane & 15;      // 4-col group
        const int rowt = lane >> 4;    // 0..3
#pragma unroll
        for (int lt = 0; lt < 2; ++lt) {
            if (lt == 0 || has2) {
                const int gt = 2 * c + lt;
#pragma unroll
                for (int p = 0; p < 4; ++p) {
                    int rr = p * 4 + rowt;         // row in tile
                    int lr = lt * 16 + rr;         // local row 0..31
                    int n  = gt * 16 + rr;         // global row
                    int uid = 0, rid = 0;
                    float4 v = make_float4(0.f, 0.f, 0.f, 0.f);
                    if (n < N_SZ) {
                        int2 pr = ((const int2*)pad)[b * N_SZ + n];
                        uid = pr.x; rid = pr.y;
                        v = *(const float4*)(user_emb + (size_t)uid * 64 + dq * 4);
                    }
                    __bf16 h0 = (__bf16)v.x, h1 = (__bf16)v.y, h2 = (__bf16)v.z, h3 = (__bf16)v.w;
                    bf16x4 hv = { h0, h1, h2, h3 };
                    bf16x4 lv = { (__bf16)(v.x - (float)h0), (__bf16)(v.y - (float)h1),
                                  (__bf16)(v.z - (float)h2), (__bf16)(v.w - (float)h3) };
                    int g = dq >> 1;
                    int idx = lr * 64 + ((g ^ (lr & 7)) << 3) + (dq & 1) * 4;
                    *(bf16x4*)&XH[idx] = hv;
                    *(bf16x4*)&XL[idx] = lv;
                    if (dq == 0) {
                        rid_s[lr]  = (n < N_SZ) ? rid : 0;
                        mask_s[lr] = (n < N_SZ && uid > 0) ? 1.f : 0.f;
                    }
                }
            }
        }
    }
    // no barrier: single wave; compiler inserts lgkmcnt waits for LDS reads.

    auto loadA = [&](const __bf16* P, int lt, bf16x8 A[2]) {
        int ln = lt * 16 + lrow;
        int s = ln & 7;
#pragma unroll
        for (int kt = 0; kt < 2; ++kt)
            A[kt] = *(const bf16x8*)&P[ln * 64 + (((kt * 4 + lgrp) ^ s) << 3)];
    };

#define LOAD_B(LAYER)                                                            \
    u32x4 bh[4][2], bl[4][2];                                                    \
    _Pragma("unroll")                                                            \
    for (int ct = 0; ct < 4; ++ct)                                               \
        _Pragma("unroll")                                                        \
        for (int kt = 0; kt < 2; ++kt) {                                         \
            int fb = (((LAYER) * 2 + kt) * 4 + ct) * 2;                          \
            bh[ct][kt] = *(const u32x4*)&bfrag[(fb + 0) * 256 + lane * 4];       \
            bl[ct][kt] = *(const u32x4*)&bfrag[(fb + 1) * 256 + lane * 4];       \
        }

#define MFMA3(ACC)                                                               \
    _Pragma("unroll")                                                            \
    for (int ct = 0; ct < 4; ++ct)                                               \
        _Pragma("unroll")                                                        \
        for (int kt = 0; kt < 2; ++kt) {                                         \
            bf16x8 BH = __builtin_bit_cast(bf16x8, bh[ct][kt]);                  \
            bf16x8 BL = __builtin_bit_cast(bf16x8, bl[ct][kt]);                  \
            ACC[ct] = __builtin_amdgcn_mfma_f32_16x16x32_bf16(AL[kt], BH, ACC[ct], 0, 0, 0); \
            ACC[ct] = __builtin_amdgcn_mfma_f32_16x16x32_bf16(AH[kt], BL, ACC[ct], 0, 0, 0); \
            ACC[ct] = __builtin_amdgcn_mfma_f32_16x16x32_bf16(AH[kt], BH, ACC[ct], 0, 0, 0); \
        }

#define MFMA2(ACC)                                                               \
    _Pragma("unroll")                                                            \
    for (int ct = 0; ct < 4; ++ct)                                               \
        _Pragma("unroll")                                                        \
        for (int kt = 0; kt < 2; ++kt) {                                         \
            bf16x8 BH = __builtin_bit_cast(bf16x8, bh[ct][kt]);                  \
            bf16x8 BL = __builtin_bit_cast(bf16x8, bl[ct][kt]);                  \
            ACC[ct] = __builtin_amdgcn_mfma_f32_16x16x32_bf16(AH[kt], BL, ACC[ct], 0, 0, 0); \
            ACC[ct] = __builtin_amdgcn_mfma_f32_16x16x32_bf16(AH[kt], BH, ACC[ct], 0, 0, 0); \
        }

    f32x4 f_reg[2][4];   // both tiles' layer-2 outputs (exact f32 for agg)

    // ---- layer 1: h = relu(P @ W1a^T + erc[rid]) ----
    {
        LOAD_B(0)
#pragma unroll
        for (int lt = 0; lt < 2; ++lt) {
            if (lt == 0 || has2) {
                bf16x8 AH[2], AL[2];
                loadA(XH, lt, AH);
                loadA(XL, lt, AL);
                int nr[4], ridr[4];
#pragma unroll
                for (int r = 0; r < 4; ++r) { nr[r] = lt * 16 + lgrp * 4 + r; ridr[r] = rid_s[nr[r]]; }
                f32x4 acc[4];
#pragma unroll
                for (int ct = 0; ct < 4; ++ct) {
                    int k = ct * 16 + lcol;
#pragma unroll
                    for (int r = 0; r < 4; ++r) acc[ct][r] = erc_s[ridr[r] * 65 + k];
                }
                MFMA3(acc)
#pragma unroll
                for (int ct = 0; ct < 4; ++ct) {
                    int col = ct * 16 + lcol;
#pragma unroll
                    for (int r = 0; r < 4; ++r) {
                        float hv = fmaxf(acc[ct][r], 0.f);
                        __bf16 hh = (__bf16)hv;
                        __bf16 ll = (__bf16)(hv - (float)hh);
                        int ln = nr[r];
                        int idx = ln * 64 + (((col >> 3) ^ (ln & 7)) << 3) + (col & 7);
                        XH[idx] = hh;
                        XL[idx] = ll;
                    }
                }
            }
        }
    }

    // ---- layer 2: f = h @ W2^T + b2 (regs; hi stored for layer 3) ----
    {
        LOAD_B(1)
#pragma unroll
        for (int lt = 0; lt < 2; ++lt) {
            if (lt == 0 || has2) {
                bf16x8 AH[2], AL[2];
                loadA(XH, lt, AH);
                loadA(XL, lt, AL);
                f32x4 (&acc)[4] = f_reg[lt];
#pragma unroll
                for (int ct = 0; ct < 4; ++ct) {
                    float bb = b2_s[ct * 16 + lcol];
#pragma unroll
                    for (int r = 0; r < 4; ++r) acc[ct][r] = bb;
                }
                MFMA3(acc)
#pragma unroll
                for (int ct = 0; ct < 4; ++ct) {
                    int col = ct * 16 + lcol;
#pragma unroll
                    for (int r = 0; r < 4; ++r) {
                        int ln = lt * 16 + lgrp * 4 + r;
                        int idx = ln * 64 + (((col >> 3) ^ (ln & 7)) << 3) + (col & 7);
                        XH[idx] = (__bf16)acc[ct][r];   // hi only — layer-3 A operand
                    }
                }
            }
        }
    }

    // ---- layer 3 + miu + in-register agg ----
    float aggr[4] = { 0.f, 0.f, 0.f, 0.f };
    float swave = 0.f;
    {
        LOAD_B(2)
#pragma unroll
        for (int lt = 0; lt < 2; ++lt) {
            if (lt == 0 || has2) {
                bf16x8 AH[2];
                loadA(XH, lt, AH);
                float maskr[4];
#pragma unroll
                for (int r = 0; r < 4; ++r) maskr[r] = mask_s[lt * 16 + lgrp * 4 + r];
                f32x4 acc[4];
#pragma unroll
                for (int ct = 0; ct < 4; ++ct) {
                    int k = ct * 16 + lcol;
                    float bb = ab1_s[k], qq = qc_s[k];
#pragma unroll
                    for (int r = 0; r < 4; ++r) acc[ct][r] = fmaf(maskr[r], qq, bb);
                }
                MFMA2(acc)
                float pm[4] = { 0.f, 0.f, 0.f, 0.f };
#pragma unroll
                for (int ct = 0; ct < 4; ++ct) {
                    float w2v = aw2_s[ct * 16 + lcol];
#pragma unroll
                    for (int r = 0; r < 4; ++r)
                        pm[r] = fmaf(fmaxf(acc[ct][r], 0.f), w2v, pm[r]);
                }
#pragma unroll
                for (int off = 1; off <= 8; off <<= 1) {
#pragma unroll
                    for (int r = 0; r < 4; ++r) pm[r] += __shfl_xor(pm[r], off);
                }
                float miur[4];
#pragma unroll
                for (int r = 0; r < 4; ++r) {
                    miur[r] = __expf(pm[r] + ab2) * maskr[r];
                    swave += miur[r];
                }
#pragma unroll
                for (int ct = 0; ct < 4; ++ct)
#pragma unroll
                    for (int r = 0; r < 4; ++r)
                        aggr[ct] = fmaf(miur[r], f_reg[lt][ct][r], aggr[ct]);
            }
        }
    }

    // ---- reduce over lane groups, then atomic partials into ws ----
#pragma unroll
    for (int ct = 0; ct < 4; ++ct) {
        float v = aggr[ct];
        v += __shfl_xor(v, 16);
        v += __shfl_xor(v, 32);
        aggr[ct] = v;
    }
    swave += __shfl_xor(swave, 16);
    swave += __shfl_xor(swave, 32);
    if (lane < 16) {
#pragma unroll
        for (int ct = 0; ct < 4; ++ct)
            atomicAdd(&aggbuf[b * 64 + ct * 16 + lane], aggr[ct]);
    }
    if (lane == 0)
        atomicAdd(&scbuf[b], swave);
}

// ---- normalize + z = relu(agg @ agg_w^T + agg_b) ----
__global__ __launch_bounds__(256) void final_z(const float* __restrict__ aggbuf,
                                               const float* __restrict__ scbuf,
                                               const float* __restrict__ agg_w,
                                               const float* __restrict__ agg_b,
                                               float* __restrict__ out) {
    __shared__ float aws[64 * 65];
    int t = threadIdx.x;
    for (int idx = t; idx < 4096; idx += 256)
        aws[(idx >> 6) * 65 + (idx & 63)] = agg_w[idx];
    __syncthreads();
    int g = t >> 6, k = t & 63;
    for (int bi = 0; bi < 2; ++bi) {
        int b = blockIdx.x * 8 + g * 2 + bi;
        const float* arow = aggbuf + b * 64;   // wave-uniform -> s_load
        float inv = 1.f / (scbuf[b] + 1e-10f);
        float dot = 0.f;
        for (int d = 0; d < 64; ++d)
            dot = fmaf(aws[k * 65 + d], arow[d], dot);
        out[b * 64 + k] = fmaxf(fmaf(inv, dot, agg_b[k]), 0.f);
    }
}

extern "C" void kernel_launch(void* const* d_in, const int* in_sizes, int n_in,
                              void* d_out, int out_size, void* d_ws, size_t ws_size,
                              hipStream_t stream) {
    const int*   iids     = (const int*)d_in[0];
    const int*   pad      = (const int*)d_in[1];
    const float* user_emb = (const float*)d_in[2];
    const float* item_emb = (const float*)d_in[3];
    const float* rate_emb = (const float*)d_in[4];
    const float* gu_w1    = (const float*)d_in[5];
    const float* gu_b1    = (const float*)d_in[6];
    const float* gu_w2    = (const float*)d_in[7];
    const float* gu_b2    = (const float*)d_in[8];
    const float* att_w1   = (const float*)d_in[9];
    const float* att_b1   = (const float*)d_in[10];
    const float* att_w2   = (const float*)d_in[11];
    const float* att_b2   = (const float*)d_in[12];
    const float* agg_w    = (const float*)d_in[13];
    const float* agg_b    = (const float*)d_in[14];
    float* ws  = (float*)d_ws;
    float* out = (float*)d_out;

    hipLaunchKernelGGL(prep1, dim3(1), dim3(256), 0, stream,
                       gu_w1, gu_b1, gu_w2, att_w1, rate_emb, ws);
    hipLaunchKernelGGL(prep2_qc, dim3(B_SZ), dim3(64), 0, stream,
                       iids, item_emb, ws, ws + OFF_QC);
    hipMemsetAsync(ws + OFF_AGG, 0, (size_t)(B_SZ * 64 + B_SZ) * sizeof(float), stream);
    hipLaunchKernelGGL(fused_main, dim3(B_SZ * 7), dim3(64), 0, stream,
                       pad, user_emb, gu_b2, att_b1, att_w2, att_b2,
                       ws, ws + OFF_AGG, ws + OFF_SC);
    hipLaunchKernelGGL(final_z, dim3(B_SZ / 8), dim3(256), 0, stream,
                       ws + OFF_AGG, ws + OFF_SC, agg_w, agg_b, out);
}